// Round 1
// baseline (250.341 us; speedup 1.0000x reference)
//
#include <hip/hip_runtime.h>
#include <math.h>

#define L_DIM 8192
#define NCH   64
#define NBATCH 32
#define TW    64
#define N_TILES 4096            // NBATCH * (L_DIM / TW)
#define M_TOT_F 262144.0f

// ws float layout:
//  [0, 4096)    gram (G = x x^T partial sums, atomically accumulated)
//  [4096, 4160) per-channel sums
//  [4160, 8256) wm (whitening matrix)
//  [8256, 8320) bias = -wm @ mean

__global__ __launch_bounds__(256) void zero_ws_kernel(float* __restrict__ ws) {
    int i = blockIdx.x * 256 + threadIdx.x;
    if (i < 4160) ws[i] = 0.0f;
}

__device__ __forceinline__ void fma16(float (&acc)[4][4], const float4 av, const float4 bv) {
    acc[0][0] += av.x * bv.x; acc[0][1] += av.x * bv.y; acc[0][2] += av.x * bv.z; acc[0][3] += av.x * bv.w;
    acc[1][0] += av.y * bv.x; acc[1][1] += av.y * bv.y; acc[1][2] += av.y * bv.z; acc[1][3] += av.y * bv.w;
    acc[2][0] += av.z * bv.x; acc[2][1] += av.z * bv.y; acc[2][2] += av.z * bv.z; acc[2][3] += av.z * bv.w;
    acc[3][0] += av.w * bv.x; acc[3][1] += av.w * bv.y; acc[3][2] += av.w * bv.z; acc[3][3] += av.w * bv.w;
}

// ---------------- K1: Gram matrix + channel sums ----------------
__global__ __launch_bounds__(256) void gram_kernel(const float* __restrict__ X,
                                                   float* __restrict__ ws) {
    __shared__ __align__(16) float lds[TW][NCH];     // lds[jj][c]
    const int tid  = threadIdx.x;
    const int ty   = tid >> 4;          // 0..15
    const int tx   = tid & 15;          // 0..15
    const int lrow = tid >> 2;          // 0..63 (channel row this thread loads)
    const int lq   = (tid & 3) << 4;    // 0,16,32,48 (column chunk)

    float acc[4][4];
#pragma unroll
    for (int i = 0; i < 4; ++i)
#pragma unroll
        for (int j = 0; j < 4; ++j) acc[i][j] = 0.0f;
    float sacc[4] = {0.f, 0.f, 0.f, 0.f};

    const int TPB = 8;                  // tiles per block: 512 blocks * 8 = 4096
    const int tile0 = blockIdx.x * TPB;

    // prefetch tile 0
    int tile = tile0;
    const float* src = X + (((size_t)(tile >> 7)) * NCH + lrow) * L_DIM + ((tile & 127) << 6) + lq;
    float4 v0 = ((const float4*)src)[0];
    float4 v1 = ((const float4*)src)[1];
    float4 v2 = ((const float4*)src)[2];
    float4 v3 = ((const float4*)src)[3];

    for (int t = 0; t < TPB; ++t) {
        __syncthreads();   // previous tile's compute done before overwriting LDS
        lds[lq +  0][lrow] = v0.x; lds[lq +  1][lrow] = v0.y; lds[lq +  2][lrow] = v0.z; lds[lq +  3][lrow] = v0.w;
        lds[lq +  4][lrow] = v1.x; lds[lq +  5][lrow] = v1.y; lds[lq +  6][lrow] = v1.z; lds[lq +  7][lrow] = v1.w;
        lds[lq +  8][lrow] = v2.x; lds[lq +  9][lrow] = v2.y; lds[lq + 10][lrow] = v2.z; lds[lq + 11][lrow] = v2.w;
        lds[lq + 12][lrow] = v3.x; lds[lq + 13][lrow] = v3.y; lds[lq + 14][lrow] = v3.z; lds[lq + 15][lrow] = v3.w;
        __syncthreads();
        if (t + 1 < TPB) {   // software prefetch next tile (latency hidden by compute)
            int tn = tile0 + t + 1;
            const float* s2 = X + (((size_t)(tn >> 7)) * NCH + lrow) * L_DIM + ((tn & 127) << 6) + lq;
            v0 = ((const float4*)s2)[0];
            v1 = ((const float4*)s2)[1];
            v2 = ((const float4*)s2)[2];
            v3 = ((const float4*)s2)[3];
        }
#pragma unroll 8
        for (int jj = 0; jj < TW; ++jj) {
            float4 av = *(const float4*)&lds[jj][ty << 2];
            float4 bv = *(const float4*)&lds[jj][tx << 2];
            fma16(acc, av, bv);
            if (tx == 0) { sacc[0] += av.x; sacc[1] += av.y; sacc[2] += av.z; sacc[3] += av.w; }
        }
    }

    float* gram = ws;
#pragma unroll
    for (int i = 0; i < 4; ++i)
#pragma unroll
        for (int j = 0; j < 4; ++j)
            atomicAdd(&gram[((ty << 2) + i) * NCH + (tx << 2) + j], acc[i][j]);
    if (tx == 0) {
#pragma unroll
        for (int i = 0; i < 4; ++i) atomicAdd(&ws[4096 + (ty << 2) + i], sacc[i]);
    }
}

// ---------------- K2: Sigma -> Newton-Schulz -> wm, bias (single block) ----------------
// All matrices in the chain are symmetric (polynomials of Sigma_N), so the
// A-operand of each matmul is read column-contiguously: A[r][k] == A[k][r].
__device__ __forceinline__ void mm64(float* __restrict__ C, const float* __restrict__ A,
                                     const float* __restrict__ B, int ty, int tx) {
    float acc[4][4];
#pragma unroll
    for (int i = 0; i < 4; ++i)
#pragma unroll
        for (int j = 0; j < 4; ++j) acc[i][j] = 0.0f;
#pragma unroll 4
    for (int k = 0; k < 64; ++k) {
        float4 av = *(const float4*)&A[k * 64 + (ty << 2)];   // A symmetric
        float4 bv = *(const float4*)&B[k * 64 + (tx << 2)];
        fma16(acc, av, bv);
    }
#pragma unroll
    for (int i = 0; i < 4; ++i)
#pragma unroll
        for (int j = 0; j < 4; ++j)
            C[((ty << 2) + i) * 64 + (tx << 2) + j] = acc[i][j];
}

__global__ __launch_bounds__(256) void ns_kernel(float* __restrict__ ws) {
    __shared__ __align__(16) float S[4096];
    __shared__ __align__(16) float P[4096];
    __shared__ __align__(16) float A[4096];
    __shared__ __align__(16) float Bm[4096];
    __shared__ float meanv[64];
    __shared__ float scal[2];

    const int tid = threadIdx.x;
    const int ty = tid >> 4, tx = tid & 15;
    const float inv_m = 1.0f / M_TOT_F;

    if (tid < 64) meanv[tid] = ws[4096 + tid] * inv_m;
    __syncthreads();

    for (int e = tid; e < 4096; e += 256) {
        int i = e >> 6, j = e & 63;
        S[e] = ws[e] * inv_m - meanv[i] * meanv[j] + ((i == j) ? 1e-5f : 0.0f);
        P[e] = (i == j) ? 1.0f : 0.0f;
    }
    __syncthreads();

    if (tid == 0) {
        float tr = 0.0f;
        for (int i = 0; i < 64; ++i) tr += S[i * 65];
        float rTr = 1.0f / tr;
        scal[0] = rTr;
        scal[1] = sqrtf(rTr);
    }
    __syncthreads();
    const float rTr = scal[0];
    for (int e = tid; e < 4096; e += 256) S[e] *= rTr;   // Sigma_N
    __syncthreads();

    for (int it = 0; it < 5; ++it) {
        mm64(A, P, P, ty, tx);      // A = P*P
        __syncthreads();
        mm64(Bm, A, P, ty, tx);     // B = P^3
        __syncthreads();
        // C = B*Sigma_N (into regs), P = 1.5P - 0.5C
        float acc[4][4];
#pragma unroll
        for (int i = 0; i < 4; ++i)
#pragma unroll
            for (int j = 0; j < 4; ++j) acc[i][j] = 0.0f;
#pragma unroll 4
        for (int k = 0; k < 64; ++k) {
            float4 av = *(const float4*)&Bm[k * 64 + (ty << 2)];
            float4 bv = *(const float4*)&S[k * 64 + (tx << 2)];
            fma16(acc, av, bv);
        }
#pragma unroll
        for (int i = 0; i < 4; ++i)
#pragma unroll
            for (int j = 0; j < 4; ++j) {
                int idx = ((ty << 2) + i) * 64 + (tx << 2) + j;
                P[idx] = 1.5f * P[idx] - 0.5f * acc[i][j];
            }
        __syncthreads();
    }

    const float s_sq = scal[1];
    for (int e = tid; e < 4096; e += 256) ws[4160 + e] = P[e] * s_sq;   // wm
    if (tid < 64) {
        float a = 0.0f;
        for (int k = 0; k < 64; ++k) a += P[tid * 64 + k] * meanv[k];
        ws[8256 + tid] = -a * s_sq;                                     // bias
    }
}

// ---------------- K3: Xn = wm @ (x - mean) applied per column ----------------
__global__ __launch_bounds__(256) void apply_kernel(const float* __restrict__ X,
                                                    float* __restrict__ Y,
                                                    const float* __restrict__ ws) {
    __shared__ __align__(16) float wm[4096];
    __shared__ __align__(16) float xt[4096];   // xt[k][jj ^ swz(k)], swz(k) = (k&15)<<2
    __shared__ float bias[64];

    const int tid  = threadIdx.x;
    const int ty   = tid >> 4;
    const int tx   = tid & 15;
    const int lrow = tid >> 2;
    const int lq   = (tid & 3) << 4;
    const int swz  = (lrow & 15) << 2;

    for (int e = tid; e < 4096; e += 256) wm[e] = ws[4160 + e];
    if (tid < 64) bias[tid] = ws[8256 + tid];
    __syncthreads();
    const float4 bias4 = *(const float4*)&bias[ty << 2];

    const int TPB = 4;                  // 1024 blocks * 4 = 4096 tiles
    const int tile0 = blockIdx.x * TPB;

    int tile = tile0;
    const float* src = X + (((size_t)(tile >> 7)) * NCH + lrow) * L_DIM + ((tile & 127) << 6) + lq;
    float4 v0 = ((const float4*)src)[0];
    float4 v1 = ((const float4*)src)[1];
    float4 v2 = ((const float4*)src)[2];
    float4 v3 = ((const float4*)src)[3];

    for (int t = 0; t < TPB; ++t) {
        int cur = tile0 + t;
        int b   = cur >> 7;
        int lc  = (cur & 127) << 6;
        __syncthreads();
        *(float4*)&xt[lrow * 64 + ((lq +  0) ^ swz)] = v0;
        *(float4*)&xt[lrow * 64 + ((lq +  4) ^ swz)] = v1;
        *(float4*)&xt[lrow * 64 + ((lq +  8) ^ swz)] = v2;
        *(float4*)&xt[lrow * 64 + ((lq + 12) ^ swz)] = v3;
        __syncthreads();
        if (t + 1 < TPB) {
            int tn = tile0 + t + 1;
            const float* s2 = X + (((size_t)(tn >> 7)) * NCH + lrow) * L_DIM + ((tn & 127) << 6) + lq;
            v0 = ((const float4*)s2)[0];
            v1 = ((const float4*)s2)[1];
            v2 = ((const float4*)s2)[2];
            v3 = ((const float4*)s2)[3];
        }

        float acc[4][4];
#pragma unroll
        for (int i = 0; i < 4; ++i) {
            acc[i][0] = acc[i][1] = acc[i][2] = acc[i][3] = 0.0f;
        }
        acc[0][0] = acc[0][1] = acc[0][2] = acc[0][3] = bias4.x;
        acc[1][0] = acc[1][1] = acc[1][2] = acc[1][3] = bias4.y;
        acc[2][0] = acc[2][1] = acc[2][2] = acc[2][3] = bias4.z;
        acc[3][0] = acc[3][1] = acc[3][2] = acc[3][3] = bias4.w;

#pragma unroll 8
        for (int k = 0; k < 64; ++k) {
            float4 wv = *(const float4*)&wm[k * 64 + (ty << 2)];                // wm symmetric
            float4 xv = *(const float4*)&xt[k * 64 + (((tx << 2) ^ ((k & 15) << 2)))];
            fma16(acc, wv, xv);
        }

        float* dst = Y + ((size_t)b * NCH + (ty << 2)) * L_DIM + lc + (tx << 2);
        float4 o;
        o.x = acc[0][0]; o.y = acc[0][1]; o.z = acc[0][2]; o.w = acc[0][3];
        *(float4*)(dst + 0 * L_DIM) = o;
        o.x = acc[1][0]; o.y = acc[1][1]; o.z = acc[1][2]; o.w = acc[1][3];
        *(float4*)(dst + 1 * L_DIM) = o;
        o.x = acc[2][0]; o.y = acc[2][1]; o.z = acc[2][2]; o.w = acc[2][3];
        *(float4*)(dst + 2 * L_DIM) = o;
        o.x = acc[3][0]; o.y = acc[3][1]; o.z = acc[3][2]; o.w = acc[3][3];
        *(float4*)(dst + 3 * L_DIM) = o;
    }
}

extern "C" void kernel_launch(void* const* d_in, const int* in_sizes, int n_in,
                              void* d_out, int out_size, void* d_ws, size_t ws_size,
                              hipStream_t stream) {
    const float* X = (const float*)d_in[0];
    float* Y  = (float*)d_out;
    float* ws = (float*)d_ws;

    hipLaunchKernelGGL(zero_ws_kernel, dim3(17),   dim3(256), 0, stream, ws);
    hipLaunchKernelGGL(gram_kernel,    dim3(512),  dim3(256), 0, stream, X, ws);
    hipLaunchKernelGGL(ns_kernel,      dim3(1),    dim3(256), 0, stream, ws);
    hipLaunchKernelGGL(apply_kernel,   dim3(1024), dim3(256), 0, stream, X, Y, ws);
}

// Round 2
// 167.580 us; speedup vs baseline: 1.4939x; 1.4939x over previous
//
#include <hip/hip_runtime.h>
#include <math.h>

#define L_DIM   8192
#define NCH     64
#define M_TOT_F 262144.0f
#define EPS_F   1e-5f

typedef float f32x4 __attribute__((ext_vector_type(4)));
typedef short bf16x8 __attribute__((ext_vector_type(8)));

union U8 { unsigned u[4]; bf16x8 v; };

// split two fp32 into packed bf16 hi (truncated) and bf16 lo (residual), 2 shorts per u32
__device__ __forceinline__ void cvt2(float f0, float f1, unsigned& h, unsigned& l) {
    unsigned u0 = __float_as_uint(f0), u1 = __float_as_uint(f1);
    h = (u0 >> 16) | (u1 & 0xFFFF0000u);
    float r0 = f0 - __uint_as_float(u0 & 0xFFFF0000u);
    float r1 = f1 - __uint_as_float(u1 & 0xFFFF0000u);
    l = (__float_as_uint(r0) >> 16) | (__float_as_uint(r1) & 0xFFFF0000u);
}

__device__ __forceinline__ void cvt8(const float* p, bf16x8& hi, bf16x8& lo) {
    float4 f0 = *(const float4*)p;
    float4 f1 = *(const float4*)(p + 4);
    U8 H, L;
    cvt2(f0.x, f0.y, H.u[0], L.u[0]);
    cvt2(f0.z, f0.w, H.u[1], L.u[1]);
    cvt2(f1.x, f1.y, H.u[2], L.u[2]);
    cvt2(f1.z, f1.w, H.u[3], L.u[3]);
    hi = H.v; lo = L.v;
}

__device__ __forceinline__ f32x4 mfma16(bf16x8 a, bf16x8 b, f32x4 c) {
    return __builtin_amdgcn_mfma_f32_16x16x32_bf16(a, b, c, 0, 0, 0);
}

__device__ __forceinline__ f32x4 fzero() {
    f32x4 z; z[0] = 0.f; z[1] = 0.f; z[2] = 0.f; z[3] = 0.f; return z;
}

// ---------------- K1: Gram partials (G1=hi*hi^T, G2=hi*lo^T) + row sums ----------------
// 512 blocks x 8 tiles (tile = 64 ch x 64 samples).  Partials -> scratch (d_out).
// Partial layout per block (stride 8256 floats): [0,4096) G1, [4096,8192) G2, [8192,8256) sums
#define GTPB 8
__global__ __launch_bounds__(256) void gram_kernel(const float* __restrict__ X,
                                                   float* __restrict__ P) {
    __shared__ __align__(16) unsigned short hplane[64 * 72];
    __shared__ __align__(16) unsigned short lplane[64 * 72];
    const int tid  = threadIdx.x;
    const int w    = tid >> 6;          // wave 0..3 -> row strip 16w
    const int lane = tid & 63;
    const int m    = lane & 15;
    const int q    = lane >> 4;
    const int lrow = tid >> 2;          // staging row 0..63
    const int lq16 = (tid & 3) << 4;    // staging col chunk

    f32x4 acc1[4], acc2[4];
#pragma unroll
    for (int nb = 0; nb < 4; ++nb) { acc1[nb] = fzero(); acc2[nb] = fzero(); }
    float sacc = 0.f;

    const int tile0 = blockIdx.x * GTPB;
    float4 v[4];
    {
        int t = tile0;
        const float* src = X + ((size_t)((t >> 7) * NCH + lrow)) * L_DIM + ((t & 127) << 6) + lq16;
#pragma unroll
        for (int i = 0; i < 4; ++i) v[i] = ((const float4*)src)[i];
    }

    for (int t = 0; t < GTPB; ++t) {
#pragma unroll
        for (int i = 0; i < 4; ++i) sacc += v[i].x + v[i].y + v[i].z + v[i].w;
        __syncthreads();
#pragma unroll
        for (int i = 0; i < 4; ++i) {
            unsigned h0, l0, h1, l1;
            cvt2(v[i].x, v[i].y, h0, l0);
            cvt2(v[i].z, v[i].w, h1, l1);
            uint2 hh; hh.x = h0; hh.y = h1;
            uint2 ll; ll.x = l0; ll.y = l1;
            *(uint2*)&hplane[lrow * 72 + lq16 + 4 * i] = hh;
            *(uint2*)&lplane[lrow * 72 + lq16 + 4 * i] = ll;
        }
        __syncthreads();
        if (t + 1 < GTPB) {
            int tn = tile0 + t + 1;
            const float* src = X + ((size_t)((tn >> 7) * NCH + lrow)) * L_DIM + ((tn & 127) << 6) + lq16;
#pragma unroll
            for (int i = 0; i < 4; ++i) v[i] = ((const float4*)src)[i];
        }
#pragma unroll
        for (int k0 = 0; k0 < 64; k0 += 32) {
            bf16x8 a = *(const bf16x8*)&hplane[(16 * w + m) * 72 + k0 + 8 * q];
#pragma unroll
            for (int nb = 0; nb < 4; ++nb) {
                bf16x8 bh = *(const bf16x8*)&hplane[(16 * nb + m) * 72 + k0 + 8 * q];
                bf16x8 bl = *(const bf16x8*)&lplane[(16 * nb + m) * 72 + k0 + 8 * q];
                acc1[nb] = mfma16(a, bh, acc1[nb]);
                acc2[nb] = mfma16(a, bl, acc2[nb]);
            }
        }
    }

    float* base = P + (size_t)blockIdx.x * 8256;
#pragma unroll
    for (int nb = 0; nb < 4; ++nb)
#pragma unroll
        for (int r = 0; r < 4; ++r) {
            int grow = 16 * w + 4 * q + r;
            int gcol = 16 * nb + m;
            base[grow * 64 + gcol]        = acc1[nb][r];
            base[4096 + grow * 64 + gcol] = acc2[nb][r];
        }
    // row sums: 4 threads share a row
    sacc += __shfl_xor(sacc, 1);
    sacc += __shfl_xor(sacc, 2);
    if ((tid & 3) == 0) base[8192 + lrow] = sacc;
}

// ---------------- K1b: reduce 512 partials -> ws[0..8256) ----------------
__global__ __launch_bounds__(256) void reduce_kernel(const float* __restrict__ P,
                                                     float* __restrict__ ws) {
    const int tid = threadIdx.x;
    const int w = tid >> 6, lane = tid & 63;
    const int e0 = blockIdx.x * 64;
    float a = 0.f;
#pragma unroll 8
    for (int i = 0; i < 128; ++i)
        a += P[(size_t)(w * 128 + i) * 8256 + e0 + lane];
    __shared__ float red[4][64];
    red[w][lane] = a;
    __syncthreads();
    if (w == 0)
        ws[e0 + lane] = red[0][lane] + red[1][lane] + red[2][lane] + red[3][lane];
}

// ---------------- K2: Sigma -> Newton-Schulz (MFMA hi/lo) -> wm planes + bias ----------
// All NS iterates are polynomials of Sigma_N -> symmetric -> read both operands row-wise.
__device__ __forceinline__ void mm_sym(float* __restrict__ D, const float* __restrict__ A,
                                       const float* __restrict__ B, int w, int m, int q) {
    f32x4 acc[4];
#pragma unroll
    for (int nb = 0; nb < 4; ++nb) acc[nb] = fzero();
#pragma unroll
    for (int k0 = 0; k0 < 64; k0 += 32) {
        bf16x8 ah, al;
        cvt8(&A[(16 * w + m) * 68 + k0 + 8 * q], ah, al);
#pragma unroll
        for (int nb = 0; nb < 4; ++nb) {
            bf16x8 bh, bl;
            cvt8(&B[(16 * nb + m) * 68 + k0 + 8 * q], bh, bl);
            acc[nb] = mfma16(ah, bh, acc[nb]);
            acc[nb] = mfma16(ah, bl, acc[nb]);
            acc[nb] = mfma16(al, bh, acc[nb]);
        }
    }
#pragma unroll
    for (int nb = 0; nb < 4; ++nb)
#pragma unroll
        for (int r = 0; r < 4; ++r)
            D[(16 * w + 4 * q + r) * 68 + 16 * nb + m] = acc[nb][r];
}

__global__ __launch_bounds__(256) void ns_kernel(float* __restrict__ ws) {
    __shared__ __align__(16) float S[64 * 68];
    __shared__ __align__(16) float Pm[64 * 68];
    __shared__ __align__(16) float T1[64 * 68];
    __shared__ __align__(16) float T2[64 * 68];
    __shared__ float mu[64];
    __shared__ float scal[2];

    const int tid = threadIdx.x;
    const int w = tid >> 6, lane = tid & 63;
    const int m = lane & 15, q = lane >> 4;
    const float inv_m = 1.0f / M_TOT_F;

    if (tid < 64) mu[tid] = ws[8192 + tid] * inv_m;
    __syncthreads();

    for (int e = tid; e < 4096; e += 256) {
        int i = e >> 6, j = e & 63;
        float g = (ws[e] + ws[4096 + e] + ws[4096 + (j << 6) + i]) * inv_m;
        S[i * 68 + j]  = g - mu[i] * mu[j] + ((i == j) ? EPS_F : 0.f);
        Pm[i * 68 + j] = (i == j) ? 1.f : 0.f;
    }
    __syncthreads();

    if (tid < 64) {
        float v = S[tid * 68 + tid];
#pragma unroll
        for (int off = 32; off >= 1; off >>= 1) v += __shfl_xor(v, off);
        if (tid == 0) { scal[0] = 1.0f / v; scal[1] = sqrtf(1.0f / v); }
    }
    __syncthreads();
    const float rTr = scal[0];
    for (int e = tid; e < 4096; e += 256) S[(e >> 6) * 68 + (e & 63)] *= rTr;
    __syncthreads();

    for (int it = 0; it < 5; ++it) {
        mm_sym(T1, Pm, Pm, w, m, q);   // P^2
        __syncthreads();
        mm_sym(T2, T1, Pm, w, m, q);   // P^3
        __syncthreads();
        // C = P^3 * Sigma_N; P = 1.5P - 0.5C
        f32x4 acc[4];
#pragma unroll
        for (int nb = 0; nb < 4; ++nb) acc[nb] = fzero();
#pragma unroll
        for (int k0 = 0; k0 < 64; k0 += 32) {
            bf16x8 ah, al;
            cvt8(&T2[(16 * w + m) * 68 + k0 + 8 * q], ah, al);
#pragma unroll
            for (int nb = 0; nb < 4; ++nb) {
                bf16x8 bh, bl;
                cvt8(&S[(16 * nb + m) * 68 + k0 + 8 * q], bh, bl);
                acc[nb] = mfma16(ah, bh, acc[nb]);
                acc[nb] = mfma16(ah, bl, acc[nb]);
                acc[nb] = mfma16(al, bh, acc[nb]);
            }
        }
#pragma unroll
        for (int nb = 0; nb < 4; ++nb)
#pragma unroll
            for (int r = 0; r < 4; ++r) {
                int idx = (16 * w + 4 * q + r) * 68 + 16 * nb + m;
                Pm[idx] = 1.5f * Pm[idx] - 0.5f * acc[nb][r];
            }
        __syncthreads();
    }

    // epilogue: wm = P*sqrt(rTr) -> bf16 hi/lo planes into dead gram region; bias fp32
    const float s = scal[1];
    unsigned short* hp = (unsigned short*)ws;          // [0,4096) shorts
    unsigned short* lp = hp + 4096;
    for (int e = tid; e < 4096; e += 256) {
        int i = e >> 6, j = e & 63;
        float v = Pm[i * 68 + j] * s;
        unsigned u = __float_as_uint(v);
        hp[e] = (unsigned short)(u >> 16);
        float r = v - __uint_as_float(u & 0xFFFF0000u);
        lp[e] = (unsigned short)(__float_as_uint(r) >> 16);
    }
    if (tid < 64) {
        float a = 0.f;
#pragma unroll 8
        for (int k = 0; k < 64; ++k) a += Pm[tid * 68 + k] * mu[k];
        ws[8256 + tid] = -a * s;
    }
}

// ---------------- K3: Y = wm @ x + bias  (wm frags in regs, x direct from global) -------
#define ATPB 4
__global__ __launch_bounds__(256) void apply_kernel(const float* __restrict__ X,
                                                    float* __restrict__ Y,
                                                    const float* __restrict__ ws) {
    const int tid  = threadIdx.x;
    const int w    = tid >> 6;
    const int lane = tid & 63;
    const int m    = lane & 15;
    const int q    = lane >> 4;

    const unsigned short* hp = (const unsigned short*)ws;
    const unsigned short* lp = hp + 4096;

    bf16x8 Ah[2], Al[2];
#pragma unroll
    for (int kk = 0; kk < 2; ++kk) {
        Ah[kk] = *(const bf16x8*)&hp[(16 * w + m) * 64 + 32 * kk + 8 * q];
        Al[kk] = *(const bf16x8*)&lp[(16 * w + m) * 64 + 32 * kk + 8 * q];
    }
    const float4 bias4 = *(const float4*)&ws[8256 + 16 * w + 4 * q];

    for (int t = 0; t < ATPB; ++t) {
        int tile = blockIdx.x * ATPB + t;
        int bidx = tile >> 7;
        int l0   = (tile & 127) << 6;
        const float* xb = X + (size_t)bidx * NCH * L_DIM + l0;

        f32x4 acc[4];
#pragma unroll
        for (int nb = 0; nb < 4; ++nb) {
            acc[nb][0] = bias4.x; acc[nb][1] = bias4.y;
            acc[nb][2] = bias4.z; acc[nb][3] = bias4.w;
        }
#pragma unroll
        for (int k0 = 0; k0 < 64; k0 += 32) {
            const int kk = k0 >> 5;
#pragma unroll
            for (int nb = 0; nb < 4; ++nb) {
                float f[8];
#pragma unroll
                for (int j = 0; j < 8; ++j)
                    f[j] = xb[(size_t)(k0 + 8 * q + j) * L_DIM + 16 * nb + m];
                U8 H, L;
                cvt2(f[0], f[1], H.u[0], L.u[0]);
                cvt2(f[2], f[3], H.u[1], L.u[1]);
                cvt2(f[4], f[5], H.u[2], L.u[2]);
                cvt2(f[6], f[7], H.u[3], L.u[3]);
                acc[nb] = mfma16(Ah[kk], H.v, acc[nb]);
                acc[nb] = mfma16(Ah[kk], L.v, acc[nb]);
                acc[nb] = mfma16(Al[kk], H.v, acc[nb]);
            }
        }
#pragma unroll
        for (int nb = 0; nb < 4; ++nb)
#pragma unroll
            for (int r = 0; r < 4; ++r)
                Y[((size_t)bidx * NCH + 16 * w + 4 * q + r) * L_DIM + l0 + 16 * nb + m] = acc[nb][r];
    }
}

extern "C" void kernel_launch(void* const* d_in, const int* in_sizes, int n_in,
                              void* d_out, int out_size, void* d_ws, size_t ws_size,
                              hipStream_t stream) {
    const float* X = (const float*)d_in[0];
    float* Y  = (float*)d_out;
    float* ws = (float*)d_ws;
    float* scratch = (float*)d_out;   // gram partials live in d_out before apply overwrites it

    hipLaunchKernelGGL(gram_kernel,   dim3(512),  dim3(256), 0, stream, X, scratch);
    hipLaunchKernelGGL(reduce_kernel, dim3(129),  dim3(256), 0, stream, scratch, ws);
    hipLaunchKernelGGL(ns_kernel,     dim3(1),    dim3(256), 0, stream, ws);
    hipLaunchKernelGGL(apply_kernel,  dim3(1024), dim3(256), 0, stream, X, Y, ws);
}

// Round 3
// 157.189 us; speedup vs baseline: 1.5926x; 1.0661x over previous
//
#include <hip/hip_runtime.h>
#include <math.h>

#define L_DIM   8192
#define NCH     64
#define M_TOT_F 262144.0f
#define EPS_F   1e-5f

typedef float f32x4 __attribute__((ext_vector_type(4)));
typedef short bf16x8 __attribute__((ext_vector_type(8)));

union U8 { unsigned u[4]; bf16x8 v; };

// split two fp32 into packed bf16 hi (truncated) and bf16 lo (residual), 2 shorts per u32
__device__ __forceinline__ void cvt2(float f0, float f1, unsigned& h, unsigned& l) {
    unsigned u0 = __float_as_uint(f0), u1 = __float_as_uint(f1);
    h = (u0 >> 16) | (u1 & 0xFFFF0000u);
    float r0 = f0 - __uint_as_float(u0 & 0xFFFF0000u);
    float r1 = f1 - __uint_as_float(u1 & 0xFFFF0000u);
    l = (__float_as_uint(r0) >> 16) | (__float_as_uint(r1) & 0xFFFF0000u);
}

__device__ __forceinline__ void cvt8(const float* p, bf16x8& hi, bf16x8& lo) {
    float4 f0 = *(const float4*)p;
    float4 f1 = *(const float4*)(p + 4);
    U8 H, L;
    cvt2(f0.x, f0.y, H.u[0], L.u[0]);
    cvt2(f0.z, f0.w, H.u[1], L.u[1]);
    cvt2(f1.x, f1.y, H.u[2], L.u[2]);
    cvt2(f1.z, f1.w, H.u[3], L.u[3]);
    hi = H.v; lo = L.v;
}

__device__ __forceinline__ f32x4 mfma16(bf16x8 a, bf16x8 b, f32x4 c) {
    return __builtin_amdgcn_mfma_f32_16x16x32_bf16(a, b, c, 0, 0, 0);
}

__device__ __forceinline__ f32x4 fzero() {
    f32x4 z; z[0] = 0.f; z[1] = 0.f; z[2] = 0.f; z[3] = 0.f; return z;
}

// ---------------- K1: Gram partials (G1=hi*hi^T, G2=hi*lo^T) + row sums ----------------
#define GTPB 8
__global__ __launch_bounds__(256) void gram_kernel(const float* __restrict__ X,
                                                   float* __restrict__ P) {
    __shared__ __align__(16) unsigned short hplane[64 * 72];
    __shared__ __align__(16) unsigned short lplane[64 * 72];
    const int tid  = threadIdx.x;
    const int w    = tid >> 6;
    const int lane = tid & 63;
    const int m    = lane & 15;
    const int q    = lane >> 4;
    const int lrow = tid >> 2;
    const int lq16 = (tid & 3) << 4;

    f32x4 acc1[4], acc2[4];
#pragma unroll
    for (int nb = 0; nb < 4; ++nb) { acc1[nb] = fzero(); acc2[nb] = fzero(); }
    float sacc = 0.f;

    const int tile0 = blockIdx.x * GTPB;
    float4 v[4];
    {
        int t = tile0;
        const float* src = X + ((size_t)((t >> 7) * NCH + lrow)) * L_DIM + ((t & 127) << 6) + lq16;
#pragma unroll
        for (int i = 0; i < 4; ++i) v[i] = ((const float4*)src)[i];
    }

    for (int t = 0; t < GTPB; ++t) {
#pragma unroll
        for (int i = 0; i < 4; ++i) sacc += v[i].x + v[i].y + v[i].z + v[i].w;
        __syncthreads();
#pragma unroll
        for (int i = 0; i < 4; ++i) {
            unsigned h0, l0, h1, l1;
            cvt2(v[i].x, v[i].y, h0, l0);
            cvt2(v[i].z, v[i].w, h1, l1);
            uint2 hh; hh.x = h0; hh.y = h1;
            uint2 ll; ll.x = l0; ll.y = l1;
            *(uint2*)&hplane[lrow * 72 + lq16 + 4 * i] = hh;
            *(uint2*)&lplane[lrow * 72 + lq16 + 4 * i] = ll;
        }
        __syncthreads();
        if (t + 1 < GTPB) {
            int tn = tile0 + t + 1;
            const float* src = X + ((size_t)((tn >> 7) * NCH + lrow)) * L_DIM + ((tn & 127) << 6) + lq16;
#pragma unroll
            for (int i = 0; i < 4; ++i) v[i] = ((const float4*)src)[i];
        }
#pragma unroll
        for (int k0 = 0; k0 < 64; k0 += 32) {
            bf16x8 a = *(const bf16x8*)&hplane[(16 * w + m) * 72 + k0 + 8 * q];
#pragma unroll
            for (int nb = 0; nb < 4; ++nb) {
                bf16x8 bh = *(const bf16x8*)&hplane[(16 * nb + m) * 72 + k0 + 8 * q];
                bf16x8 bl = *(const bf16x8*)&lplane[(16 * nb + m) * 72 + k0 + 8 * q];
                acc1[nb] = mfma16(a, bh, acc1[nb]);
                acc2[nb] = mfma16(a, bl, acc2[nb]);
            }
        }
    }

    float* base = P + (size_t)blockIdx.x * 8256;
#pragma unroll
    for (int nb = 0; nb < 4; ++nb)
#pragma unroll
        for (int r = 0; r < 4; ++r) {
            int grow = 16 * w + 4 * q + r;
            int gcol = 16 * nb + m;
            base[grow * 64 + gcol]        = acc1[nb][r];
            base[4096 + grow * 64 + gcol] = acc2[nb][r];
        }
    sacc += __shfl_xor(sacc, 1);
    sacc += __shfl_xor(sacc, 2);
    if ((tid & 3) == 0) base[8192 + lrow] = sacc;
}

// ---------------- K1b: reduce 512 partials -> ws[0..8256) ----------------
__global__ __launch_bounds__(256) void reduce_kernel(const float* __restrict__ P,
                                                     float* __restrict__ ws) {
    const int tid = threadIdx.x;
    const int w = tid >> 6, lane = tid & 63;
    const int e0 = blockIdx.x * 64;
    float a = 0.f;
#pragma unroll 8
    for (int i = 0; i < 128; ++i)
        a += P[(size_t)(w * 128 + i) * 8256 + e0 + lane];
    __shared__ float red[4][64];
    red[w][lane] = a;
    __syncthreads();
    if (w == 0)
        ws[e0 + lane] = red[0][lane] + red[1][lane] + red[2][lane] + red[3][lane];
}

// ---------------- K2: Sigma -> Newton-Schulz (MFMA hi/lo) -> wm planes + bias ----------
__device__ __forceinline__ void mm_sym(float* __restrict__ D, const float* __restrict__ A,
                                       const float* __restrict__ B, int w, int m, int q) {
    f32x4 acc[4];
#pragma unroll
    for (int nb = 0; nb < 4; ++nb) acc[nb] = fzero();
#pragma unroll
    for (int k0 = 0; k0 < 64; k0 += 32) {
        bf16x8 ah, al;
        cvt8(&A[(16 * w + m) * 68 + k0 + 8 * q], ah, al);
#pragma unroll
        for (int nb = 0; nb < 4; ++nb) {
            bf16x8 bh, bl;
            cvt8(&B[(16 * nb + m) * 68 + k0 + 8 * q], bh, bl);
            acc[nb] = mfma16(ah, bh, acc[nb]);
            acc[nb] = mfma16(ah, bl, acc[nb]);
            acc[nb] = mfma16(al, bh, acc[nb]);
        }
    }
#pragma unroll
    for (int nb = 0; nb < 4; ++nb)
#pragma unroll
        for (int r = 0; r < 4; ++r)
            D[(16 * w + 4 * q + r) * 68 + 16 * nb + m] = acc[nb][r];
}

__global__ __launch_bounds__(256) void ns_kernel(float* __restrict__ ws) {
    __shared__ __align__(16) float S[64 * 68];
    __shared__ __align__(16) float Pm[64 * 68];
    __shared__ __align__(16) float T1[64 * 68];
    __shared__ __align__(16) float T2[64 * 68];
    __shared__ float mu[64];
    __shared__ float scal[2];

    const int tid = threadIdx.x;
    const int w = tid >> 6, lane = tid & 63;
    const int m = lane & 15, q = lane >> 4;
    const float inv_m = 1.0f / M_TOT_F;

    if (tid < 64) mu[tid] = ws[8192 + tid] * inv_m;
    __syncthreads();

    for (int e = tid; e < 4096; e += 256) {
        int i = e >> 6, j = e & 63;
        float g = (ws[e] + ws[4096 + e] + ws[4096 + (j << 6) + i]) * inv_m;
        S[i * 68 + j]  = g - mu[i] * mu[j] + ((i == j) ? EPS_F : 0.f);
        Pm[i * 68 + j] = (i == j) ? 1.f : 0.f;
    }
    __syncthreads();

    if (tid < 64) {
        float v = S[tid * 68 + tid];
#pragma unroll
        for (int off = 32; off >= 1; off >>= 1) v += __shfl_xor(v, off);
        if (tid == 0) { scal[0] = 1.0f / v; scal[1] = sqrtf(1.0f / v); }
    }
    __syncthreads();
    const float rTr = scal[0];
    for (int e = tid; e < 4096; e += 256) S[(e >> 6) * 68 + (e & 63)] *= rTr;
    __syncthreads();

    for (int it = 0; it < 5; ++it) {
        mm_sym(T1, Pm, Pm, w, m, q);
        __syncthreads();
        mm_sym(T2, T1, Pm, w, m, q);
        __syncthreads();
        f32x4 acc[4];
#pragma unroll
        for (int nb = 0; nb < 4; ++nb) acc[nb] = fzero();
#pragma unroll
        for (int k0 = 0; k0 < 64; k0 += 32) {
            bf16x8 ah, al;
            cvt8(&T2[(16 * w + m) * 68 + k0 + 8 * q], ah, al);
#pragma unroll
            for (int nb = 0; nb < 4; ++nb) {
                bf16x8 bh, bl;
                cvt8(&S[(16 * nb + m) * 68 + k0 + 8 * q], bh, bl);
                acc[nb] = mfma16(ah, bh, acc[nb]);
                acc[nb] = mfma16(ah, bl, acc[nb]);
                acc[nb] = mfma16(al, bh, acc[nb]);
            }
        }
#pragma unroll
        for (int nb = 0; nb < 4; ++nb)
#pragma unroll
            for (int r = 0; r < 4; ++r) {
                int idx = (16 * w + 4 * q + r) * 68 + 16 * nb + m;
                Pm[idx] = 1.5f * Pm[idx] - 0.5f * acc[nb][r];
            }
        __syncthreads();
    }

    const float s = scal[1];
    unsigned short* hp = (unsigned short*)ws;
    unsigned short* lp = hp + 4096;
    for (int e = tid; e < 4096; e += 256) {
        int i = e >> 6, j = e & 63;
        float v = Pm[i * 68 + j] * s;
        unsigned u = __float_as_uint(v);
        hp[e] = (unsigned short)(u >> 16);
        float r = v - __uint_as_float(u & 0xFFFF0000u);
        lp[e] = (unsigned short)(__float_as_uint(r) >> 16);
    }
    if (tid < 64) {
        float a = 0.f;
#pragma unroll 8
        for (int k = 0; k < 64; ++k) a += Pm[tid * 68 + k] * mu[k];
        ws[8256 + tid] = -a * s;
    }
}

// ---------------- K3: Y = wm @ x + bias  (LDS-transposed bf16 planes, coalesced loads) --
// Plane layout: element (l, c) at short addr  l*64 + ((c>>3)^(l&7))*8 + (c&7)
// Writes: thread owns channel rows {2cp, 2cp+1}; hi/lo of the pair pack into one u32
//         -> single ds_write_b32, all 32 banks covered per l-group (conflict-free).
// Reads:  bf16x8 (b128) fragments at chunk ((4kk+q)^(l&7)) -> minimum bank rounds.
#define ATPB 4
__global__ __launch_bounds__(256) void apply_kernel(const float* __restrict__ X,
                                                    float* __restrict__ Y,
                                                    const float* __restrict__ ws) {
    __shared__ __align__(16) unsigned short hplane[4096];
    __shared__ __align__(16) unsigned short lplane[4096];
    const int tid  = threadIdx.x;
    const int w    = tid >> 6;
    const int lane = tid & 63;
    const int m    = lane & 15;
    const int q    = lane >> 4;
    const int cp   = tid & 31;      // channel pair rows 2cp, 2cp+1
    const int lg   = tid >> 5;      // 0..7

    const unsigned short* hp = (const unsigned short*)ws;
    const unsigned short* lp = hp + 4096;
    bf16x8 Ah[2], Al[2];
#pragma unroll
    for (int kk = 0; kk < 2; ++kk) {
        Ah[kk] = *(const bf16x8*)&hp[(16 * w + m) * 64 + 32 * kk + 8 * q];
        Al[kk] = *(const bf16x8*)&lp[(16 * w + m) * 64 + 32 * kk + 8 * q];
    }
    const float4 bias4 = *(const float4*)&ws[8256 + 16 * w + 4 * q];

    unsigned* hw = (unsigned*)hplane;
    unsigned* lw = (unsigned*)lplane;

    float4 va[2], vb[2];   // rows 2cp / 2cp+1, two l-groups
    {
        int tile = blockIdx.x * ATPB;
        const float* xb = X + (size_t)(tile >> 7) * (NCH * L_DIM) + ((tile & 127) << 6)
                          + (size_t)(2 * cp) * L_DIM + 4 * lg;
#pragma unroll
        for (int s = 0; s < 2; ++s) {
            va[s] = *(const float4*)(xb + 32 * s);
            vb[s] = *(const float4*)(xb + 32 * s + L_DIM);
        }
    }

    for (int t = 0; t < ATPB; ++t) {
        int tile = blockIdx.x * ATPB + t;
        int bidx = tile >> 7;
        int l0   = (tile & 127) << 6;

        __syncthreads();
#pragma unroll
        for (int s = 0; s < 2; ++s) {
            float fa[4], fb[4];
            *(float4*)fa = va[s];
            *(float4*)fb = vb[s];
#pragma unroll
            for (int i = 0; i < 4; ++i) {
                int l = 4 * lg + 32 * s + i;
                unsigned h, lo2;
                cvt2(fa[i], fb[i], h, lo2);
                int widx = l * 32 + (((cp >> 2) ^ (l & 7)) << 2) + (cp & 3);
                hw[widx] = h;
                lw[widx] = lo2;
            }
        }
        __syncthreads();

        if (t + 1 < ATPB) {
            int tn = tile + 1;
            const float* xb = X + (size_t)(tn >> 7) * (NCH * L_DIM) + ((tn & 127) << 6)
                              + (size_t)(2 * cp) * L_DIM + 4 * lg;
#pragma unroll
            for (int s = 0; s < 2; ++s) {
                va[s] = *(const float4*)(xb + 32 * s);
                vb[s] = *(const float4*)(xb + 32 * s + L_DIM);
            }
        }

        f32x4 acc[4];
#pragma unroll
        for (int nb = 0; nb < 4; ++nb) {
            acc[nb][0] = bias4.x; acc[nb][1] = bias4.y;
            acc[nb][2] = bias4.z; acc[nb][3] = bias4.w;
        }
#pragma unroll
        for (int kk = 0; kk < 2; ++kk)
#pragma unroll
            for (int nb = 0; nb < 4; ++nb) {
                int l = 16 * nb + m;
                int saddr = l * 64 + ((((4 * kk + q) ^ (l & 7))) << 3);
                bf16x8 bh = *(const bf16x8*)&hplane[saddr];
                bf16x8 bl = *(const bf16x8*)&lplane[saddr];
                acc[nb] = mfma16(Ah[kk], bh, acc[nb]);
                acc[nb] = mfma16(Ah[kk], bl, acc[nb]);
                acc[nb] = mfma16(Al[kk], bh, acc[nb]);
            }

#pragma unroll
        for (int nb = 0; nb < 4; ++nb)
#pragma unroll
            for (int rr = 0; rr < 4; ++rr)
                Y[((size_t)bidx * NCH + 16 * w + 4 * q + rr) * L_DIM + l0 + 16 * nb + m] = acc[nb][rr];
    }
}

extern "C" void kernel_launch(void* const* d_in, const int* in_sizes, int n_in,
                              void* d_out, int out_size, void* d_ws, size_t ws_size,
                              hipStream_t stream) {
    const float* X = (const float*)d_in[0];
    float* Y  = (float*)d_out;
    float* ws = (float*)d_ws;
    float* scratch = (float*)d_out;   // gram partials live in d_out before apply overwrites it

    hipLaunchKernelGGL(gram_kernel,   dim3(512),  dim3(256), 0, stream, X, scratch);
    hipLaunchKernelGGL(reduce_kernel, dim3(129),  dim3(256), 0, stream, scratch, ws);
    hipLaunchKernelGGL(ns_kernel,     dim3(1),    dim3(256), 0, stream, ws);
    hipLaunchKernelGGL(apply_kernel,  dim3(1024), dim3(256), 0, stream, X, Y, ws);
}